// Round 8
// baseline (70.780 us; speedup 1.0000x reference)
//
#include <hip/hip_runtime.h>

#define N_GENERA 4096
#define N_RANKS 6
#define N_GROUPS 256
#define NCH 7                         // 6 ranks + identity channel
#define SEG_SZ (N_RANKS * N_GROUPS)   // 1536
#define EXT_SZ (SEG_SZ + N_GENERA)    // 5632 pairs = 45 KB as float2
#define NF (N_GENERA * NCH)           // 28672 output floats per b
#define NF4 (NF / 4)                  // 7168 float4 per b

typedef float f32x4 __attribute__((ext_vector_type(4)));

// ws layout:
//   idx   [6][4096] int   @ 0        (96 KB)   CSR index lists
//   offs  [6][260]  int   @ 98304    (6.1 KB)  CSR offsets (build-time only)
//   sidx  [NF]      short @ 104704   ends at 104704+57344 = 162048
//   slotq [1536]    int4  @ 162048   (24 KB)   sorted slot -> {begAbs, len, p}
//   (round-7 bug: slotq at 160448 overlapped sidx tail by 1600 B)
#define WS_IDX_OFF   0
#define WS_OFFS_OFF  98304
#define WS_SIDX_OFF  104704
#define WS_SLOTQ_OFF 162048

__device__ __forceinline__ int imin(int a, int b) { return a < b ? a : b; }

// ---------- Kernel 0: prep = CSR (0..5) + sidx (6..117) + slotq (118) ----------
__global__ __launch_bounds__(256) void prep_kernel(
    const int* __restrict__ labels,
    int* __restrict__ idx,      // [R][N_GENERA]
    int* __restrict__ offs,     // [R][260]
    short* __restrict__ sidx,   // [NF]
    int4* __restrict__ slotq)   // [1536]
{
    const int t = threadIdx.x;

    if (blockIdx.x < N_RANKS) {
        const int r = blockIdx.x;
        const int* __restrict__ lab = labels + r * N_GENERA;

        __shared__ int cnt[N_GROUPS];
        __shared__ int scan[N_GROUPS];
        __shared__ int cur[N_GROUPS];

        cnt[t] = 0;
        __syncthreads();
        for (int i = t; i < N_GENERA; i += 256)
            atomicAdd(&cnt[lab[i]], 1);
        __syncthreads();

        int v = cnt[t];
        scan[t] = v;
        __syncthreads();
        #pragma unroll
        for (int s = 1; s < 256; s <<= 1) {
            int add = (t >= s) ? scan[t - s] : 0;
            __syncthreads();
            scan[t] += add;
            __syncthreads();
        }
        int start = scan[t] - v;          // exclusive prefix
        cur[t] = start;
        offs[r * 260 + t] = start;
        if (t == 0) offs[r * 260 + 256] = N_GENERA;
        __syncthreads();
        for (int i = t; i < N_GENERA; i += 256) {
            int p = atomicAdd(&cur[lab[i]], 1);
            idx[r * N_GENERA + p] = i;
        }
    } else if (blockIdx.x < N_RANKS + 112) {
        // sidx: output-float -> ext[]-index map (batch-independent)
        const int f = (blockIdx.x - N_RANKS) * 256 + t;   // < NF
        const int j = f / NCH;
        const int ch = f - j * NCH;
        int v;
        if (ch < N_RANKS)
            v = ch * N_GROUPS + labels[ch * N_GENERA + j];
        else
            v = SEG_SZ + j;               // identity channel -> F slot
        sidx[f] = (short)v;
    } else {
        // slotq: count-sort the 1536 (r,g) items by descending count and emit
        // {begAbs, len, p} per sorted slot. Self-contained (labels only) so it
        // cannot race with blocks 0..5 writing offs/idx. Adjacent sorted slots
        // have near-equal lengths -> wave-divergence tax in fused Phase A
        // drops from ~1.7x to ~1.1x.
        __shared__ int cnt[SEG_SZ];
        __shared__ int beg[SEG_SZ];
        __shared__ int tmp[N_GROUPS];
        __shared__ int hist[64];
        __shared__ int base[64];
        __shared__ int cur[64];
        for (int i = t; i < SEG_SZ; i += 256) cnt[i] = 0;
        if (t < 64) { hist[t] = 0; cur[t] = 0; }
        __syncthreads();
        for (int r = 0; r < N_RANKS; ++r)
            for (int i = t; i < N_GENERA; i += 256)
                atomicAdd(&cnt[r * N_GROUPS + labels[r * N_GENERA + i]], 1);
        __syncthreads();
        // per-rank exclusive prefix over the 256 groups
        for (int r = 0; r < N_RANKS; ++r) {
            int v = cnt[r * N_GROUPS + t];
            tmp[t] = v;
            __syncthreads();
            #pragma unroll
            for (int s = 1; s < 256; s <<= 1) {
                int add = (t >= s) ? tmp[t - s] : 0;
                __syncthreads();
                tmp[t] += add;
                __syncthreads();
            }
            beg[r * N_GROUPS + t] = tmp[t] - v;
            __syncthreads();               // tmp reused next rank
        }
        for (int p = t; p < SEG_SZ; p += 256)
            atomicAdd(&hist[imin(cnt[p], 63)], 1);
        __syncthreads();
        if (t < 64) {
            int bsum = 0;
            for (int c = t + 1; c < 64; ++c) bsum += hist[c];
            base[t] = bsum;               // descending-count exclusive base
        }
        __syncthreads();
        for (int p = t; p < SEG_SZ; p += 256) {
            int c = imin(cnt[p], 63);
            int slot = base[c] + atomicAdd(&cur[c], 1);
            int r = p >> 8;
            slotq[slot] = make_int4(r * N_GENERA + beg[p], cnt[p], p, 0);
        }
    }
}

// ---------- Kernel 1: fused CSR-seg + gather, TWO batch rows per block ----------
// LDS ext2[] = { seg[1536] | Frow[4096] } of float2 = {val_b0, val_b1} (45 KB).
// Phase A: 3 length-sorted slots/thread (adjacent lanes ~equal lengths);
//          per-lane CONTIGUOUS idx windows; slotq + all 14 sidx int2 loads
//          hoisted above the stage barrier so their L2 latency hides.
// Phase B: pure LDS gather (ds_read_b64 serves both b's) + 2 contiguous
//          plain float4 stores. Two barriers total.
__global__ __launch_bounds__(512) void fused_kernel(
    const float* __restrict__ F,
    const int* __restrict__ idx,
    const int4* __restrict__ slotq,
    const short* __restrict__ sidx,
    float* __restrict__ out)
{
    __shared__ float2 ext2[EXT_SZ];
    const int b0 = blockIdx.x * 2;
    const int t = threadIdx.x;

    // stage 2 F rows pair-interleaved into ext2[SEG_SZ..)
    const f32x4* Fv0 = reinterpret_cast<const f32x4*>(F + (size_t)b0 * N_GENERA);
    const f32x4* Fv1 = reinterpret_cast<const f32x4*>(F + (size_t)(b0 + 1) * N_GENERA);
    f32x4* Flv = reinterpret_cast<f32x4*>(ext2 + SEG_SZ);
    #pragma unroll
    for (int k = 0; k < 2; ++k) {
        const f32x4 a = __builtin_nontemporal_load(Fv0 + t + k * 512);
        const f32x4 c = __builtin_nontemporal_load(Fv1 + t + k * 512);
        f32x4 lo, hi;
        lo[0] = a[0]; lo[1] = c[0]; lo[2] = a[1]; lo[3] = c[1];
        hi[0] = a[2]; hi[1] = c[2]; hi[2] = a[3]; hi[3] = c[3];
        Flv[2 * (t + k * 512)]     = lo;
        Flv[2 * (t + k * 512) + 1] = hi;
    }

    // hoisted prefetches (independent of LDS / barrier)
    const int4 q0 = slotq[t];
    const int4 q1 = slotq[512 + t];
    const int4 q2 = slotq[1024 + t];
    int2 sv[14];
    const int2* __restrict__ sp = reinterpret_cast<const int2*>(sidx);
    #pragma unroll
    for (int kk = 0; kk < 14; ++kk) sv[kk] = sp[kk * 512 + t];

    __syncthreads();

    // Phase A: CSR segment sums for both b's, 3 sorted slots per thread
    const float2* __restrict__ Fl2 = ext2 + SEG_SZ;
    #pragma unroll
    for (int w = 0; w < 3; ++w) {
        const int4 q = (w == 0) ? q0 : (w == 1) ? q1 : q2;
        const int* __restrict__ ip = idx + q.x;   // contiguous per-lane window
        const int len = q.y;
        float sa = 0.f, sb = 0.f;
        int k = 0;
        for (; k + 4 <= len; k += 4) {
            int i0 = ip[k], i1 = ip[k + 1], i2 = ip[k + 2], i3 = ip[k + 3];
            float2 v0 = Fl2[i0], v1 = Fl2[i1], v2 = Fl2[i2], v3 = Fl2[i3];
            sa += (v0.x + v1.x) + (v2.x + v3.x);
            sb += (v0.y + v1.y) + (v2.y + v3.y);
        }
        for (; k < len; ++k) {
            float2 v = Fl2[ip[k]];
            sa += v.x; sb += v.y;
        }
        float2 sp2; sp2.x = sa; sp2.y = sb;
        ext2[q.z] = sp2;   // seg slot p; disjoint from F region being read
    }
    __syncthreads();

    // Phase B: 14 output float4 per b per thread, lanes contiguous per store
    f32x4* __restrict__ op0 = reinterpret_cast<f32x4*>(out) + (size_t)b0 * NF4;
    f32x4* __restrict__ op1 = op0 + NF4;
    #pragma unroll
    for (int kk = 0; kk < 14; ++kk) {
        const int q = kk * 512 + t;
        const int lo = sv[kk].x, hi = sv[kk].y;
        const int s0 = lo & 0xffff;
        const int s1 = ((unsigned)lo) >> 16;
        const int s2 = hi & 0xffff;
        const int s3 = ((unsigned)hi) >> 16;
        float2 p0 = ext2[s0];
        float2 p1 = ext2[s1];
        float2 p2 = ext2[s2];
        float2 p3 = ext2[s3];
        f32x4 va, vb;
        va[0] = p0.x; va[1] = p1.x; va[2] = p2.x; va[3] = p3.x;
        vb[0] = p0.y; vb[1] = p1.y; vb[2] = p2.y; vb[3] = p3.y;
        op0[q] = va;
        op1[q] = vb;
    }
}

extern "C" void kernel_launch(void* const* d_in, const int* in_sizes, int n_in,
                              void* d_out, int out_size, void* d_ws, size_t ws_size,
                              hipStream_t stream) {
    const float* F      = (const float*)d_in[0];
    const int*   labels = (const int*)d_in[1];
    float*       out    = (float*)d_out;

    const int B = in_sizes[0] / N_GENERA;  // 1024
    char* ws = (char*)d_ws;
    int*   idx   = (int*)(ws + WS_IDX_OFF);
    int*   offs  = (int*)(ws + WS_OFFS_OFF);
    short* sidx  = (short*)(ws + WS_SIDX_OFF);
    int4*  slotq = (int4*)(ws + WS_SLOTQ_OFF);

    prep_kernel<<<dim3(N_RANKS + 112 + 1), dim3(256), 0, stream>>>(
        labels, idx, offs, sidx, slotq);
    fused_kernel<<<dim3(B / 2), dim3(512), 0, stream>>>(F, idx, slotq, sidx, out);
}

// Round 9
// 47.471 us; speedup vs baseline: 1.4910x; 1.4910x over previous
//
#include <hip/hip_runtime.h>

#define N_GENERA 4096
#define N_RANKS 6
#define N_GROUPS 256
#define NCH 7                         // 6 ranks + identity channel
#define SEG_SZ (N_RANKS * N_GROUPS)   // 1536
#define EXT_SZ (SEG_SZ + N_GENERA)    // 5632 pairs = 45 KB as float2
#define NF (N_GENERA * NCH)           // 28672 output floats per b
#define NF4 (NF / 4)                  // 7168 float4 per b

typedef float f32x4 __attribute__((ext_vector_type(4)));

// ws layout:
//   idx  [6][4096]   int    @ 0        (96 KB)
//   offs [6][260]    int    @ 98304    (6.1 KB)
//   sidx [NF]        short  @ 104704   ends at 162048
//   segW [512][1536] float2 @ 162048   (6.29 MB) per-pair seg sums
#define WS_IDX_OFF  0
#define WS_OFFS_OFF 98304
#define WS_SIDX_OFF 104704
#define WS_SEG_OFF  162048

// ---------- Kernel 0: prep = per-rank CSR (blocks 0..5) + sidx map (blocks 6..117) ----------
__global__ __launch_bounds__(256) void prep_kernel(
    const int* __restrict__ labels,
    int* __restrict__ idx,      // [R][N_GENERA]
    int* __restrict__ offs,     // [R][260]
    short* __restrict__ sidx)   // [NF]
{
    const int t = threadIdx.x;

    if (blockIdx.x < N_RANKS) {
        const int r = blockIdx.x;
        const int* __restrict__ lab = labels + r * N_GENERA;

        __shared__ int cnt[N_GROUPS];
        __shared__ int scan[N_GROUPS];
        __shared__ int cur[N_GROUPS];

        cnt[t] = 0;
        __syncthreads();
        for (int i = t; i < N_GENERA; i += 256)
            atomicAdd(&cnt[lab[i]], 1);
        __syncthreads();

        int v = cnt[t];
        scan[t] = v;
        __syncthreads();
        #pragma unroll
        for (int s = 1; s < 256; s <<= 1) {
            int add = (t >= s) ? scan[t - s] : 0;
            __syncthreads();
            scan[t] += add;
            __syncthreads();
        }
        int start = scan[t] - v;          // exclusive prefix
        cur[t] = start;
        offs[r * 260 + t] = start;
        if (t == 0) offs[r * 260 + 256] = N_GENERA;
        __syncthreads();
        for (int i = t; i < N_GENERA; i += 256) {
            int p = atomicAdd(&cur[lab[i]], 1);
            idx[r * N_GENERA + p] = i;
        }
    } else {
        // sidx: output-float -> ext[]-index map (batch-independent)
        const int f = (blockIdx.x - N_RANKS) * 256 + t;   // < NF
        const int j = f / NCH;
        const int ch = f - j * NCH;
        int v;
        if (ch < N_RANKS)
            v = ch * N_GROUPS + labels[ch * N_GENERA + j];
        else
            v = SEG_SZ + j;               // identity channel -> F slot
        sidx[f] = (short)v;
    }
}

// ---------- Kernel 1: seg sums only (r2 Phase A verbatim), 2 b per block ----------
// LDS: Fl2[4096] float2 pairs (32 KB). Writes seg sums coalesced to ws.
__global__ __launch_bounds__(512) void seg_kernel(
    const float* __restrict__ F,
    const int* __restrict__ idx,
    const int* __restrict__ offs,
    float2* __restrict__ segW)        // [B/2][1536]
{
    __shared__ float2 Fl2[N_GENERA];
    const int b0 = blockIdx.x * 2;
    const int t = threadIdx.x;

    const f32x4* Fv0 = reinterpret_cast<const f32x4*>(F + (size_t)b0 * N_GENERA);
    const f32x4* Fv1 = reinterpret_cast<const f32x4*>(F + (size_t)(b0 + 1) * N_GENERA);
    f32x4* Flv = reinterpret_cast<f32x4*>(Fl2);
    #pragma unroll
    for (int k = 0; k < 2; ++k) {
        const f32x4 a = __builtin_nontemporal_load(Fv0 + t + k * 512);
        const f32x4 c = __builtin_nontemporal_load(Fv1 + t + k * 512);
        f32x4 lo, hi;
        lo[0] = a[0]; lo[1] = c[0]; lo[2] = a[1]; lo[3] = c[1];
        hi[0] = a[2]; hi[1] = c[2]; hi[2] = a[3]; hi[3] = c[3];
        Flv[2 * (t + k * 512)]     = lo;
        Flv[2 * (t + k * 512) + 1] = hi;
    }
    __syncthreads();

    float2* __restrict__ sw = segW + (size_t)blockIdx.x * SEG_SZ;
    #pragma unroll
    for (int w = 0; w < 3; ++w) {
        const int item = t + w * 512;
        const int r = item >> 8;
        const int g = item & 255;
        const int e = offs[r * 260 + g + 1];
        int k = offs[r * 260 + g];
        const int* __restrict__ ip = idx + r * N_GENERA;
        float sa = 0.f, sb = 0.f;
        for (; k + 4 <= e; k += 4) {
            int i0 = ip[k], i1 = ip[k + 1], i2 = ip[k + 2], i3 = ip[k + 3];
            float2 v0 = Fl2[i0], v1 = Fl2[i1], v2 = Fl2[i2], v3 = Fl2[i3];
            sa += (v0.x + v1.x) + (v2.x + v3.x);
            sb += (v0.y + v1.y) + (v2.y + v3.y);
        }
        for (; k < e; ++k) {
            float2 v = Fl2[ip[k]];
            sa += v.x; sb += v.y;
        }
        float2 sp; sp.x = sa; sp.y = sb;
        sw[item] = sp;                    // coalesced 8B stores per wave
    }
}

// ---------- Kernel 2: gather only (r2 Phase B verbatim), 2 b per block ----------
// LDS ext2[] = { seg[1536] (loaded coalesced) | Frow[4096] (staged) } (45 KB).
// No Phase A: pure stage -> barrier -> gather/store streaming.
__global__ __launch_bounds__(512) void gather_kernel(
    const float* __restrict__ F,
    const float2* __restrict__ segW,  // [B/2][1536]
    const short* __restrict__ sidx,
    float* __restrict__ out)
{
    __shared__ float2 ext2[EXT_SZ];
    const int b0 = blockIdx.x * 2;
    const int t = threadIdx.x;

    // seg -> LDS, coalesced f32x4 (768 per block)
    const f32x4* sgv = reinterpret_cast<const f32x4*>(segW + (size_t)blockIdx.x * SEG_SZ);
    f32x4* el = reinterpret_cast<f32x4*>(ext2);
    for (int i = t; i < SEG_SZ / 2; i += 512) el[i] = sgv[i];

    // stage 2 F rows pair-interleaved into ext2[SEG_SZ..)
    const f32x4* Fv0 = reinterpret_cast<const f32x4*>(F + (size_t)b0 * N_GENERA);
    const f32x4* Fv1 = reinterpret_cast<const f32x4*>(F + (size_t)(b0 + 1) * N_GENERA);
    f32x4* Flv = reinterpret_cast<f32x4*>(ext2 + SEG_SZ);
    #pragma unroll
    for (int k = 0; k < 2; ++k) {
        const f32x4 a = __builtin_nontemporal_load(Fv0 + t + k * 512);
        const f32x4 c = __builtin_nontemporal_load(Fv1 + t + k * 512);
        f32x4 lo, hi;
        lo[0] = a[0]; lo[1] = c[0]; lo[2] = a[1]; lo[3] = c[1];
        hi[0] = a[2]; hi[1] = c[2]; hi[2] = a[3]; hi[3] = c[3];
        Flv[2 * (t + k * 512)]     = lo;
        Flv[2 * (t + k * 512) + 1] = hi;
    }
    __syncthreads();

    // Phase B: 14 output float4 per b per thread, lanes contiguous per store
    f32x4* __restrict__ op0 = reinterpret_cast<f32x4*>(out) + (size_t)b0 * NF4;
    f32x4* __restrict__ op1 = op0 + NF4;
    #pragma unroll
    for (int kk = 0; kk < 14; ++kk) {
        const int q = kk * 512 + t;
        short4 s4 = *reinterpret_cast<const short4*>(sidx + q * 4);
        float2 p0 = ext2[s4.x];
        float2 p1 = ext2[s4.y];
        float2 p2 = ext2[s4.z];
        float2 p3 = ext2[s4.w];
        f32x4 va, vb;
        va[0] = p0.x; va[1] = p1.x; va[2] = p2.x; va[3] = p3.x;
        vb[0] = p0.y; vb[1] = p1.y; vb[2] = p2.y; vb[3] = p3.y;
        op0[q] = va;
        op1[q] = vb;
    }
}

// ---------- Fallback: round-2 fused kernel (if ws too small for segW) ----------
__global__ __launch_bounds__(512) void fused_kernel(
    const float* __restrict__ F,
    const int* __restrict__ idx,
    const int* __restrict__ offs,
    const short* __restrict__ sidx,
    float* __restrict__ out)
{
    __shared__ float2 ext2[EXT_SZ];
    const int b0 = blockIdx.x * 2;
    const int t = threadIdx.x;

    const f32x4* Fv0 = reinterpret_cast<const f32x4*>(F + (size_t)b0 * N_GENERA);
    const f32x4* Fv1 = reinterpret_cast<const f32x4*>(F + (size_t)(b0 + 1) * N_GENERA);
    f32x4* Flv = reinterpret_cast<f32x4*>(ext2 + SEG_SZ);
    #pragma unroll
    for (int k = 0; k < 2; ++k) {
        const f32x4 a = __builtin_nontemporal_load(Fv0 + t + k * 512);
        const f32x4 c = __builtin_nontemporal_load(Fv1 + t + k * 512);
        f32x4 lo, hi;
        lo[0] = a[0]; lo[1] = c[0]; lo[2] = a[1]; lo[3] = c[1];
        hi[0] = a[2]; hi[1] = c[2]; hi[2] = a[3]; hi[3] = c[3];
        Flv[2 * (t + k * 512)]     = lo;
        Flv[2 * (t + k * 512) + 1] = hi;
    }
    __syncthreads();

    const float2* __restrict__ Fl2 = ext2 + SEG_SZ;
    #pragma unroll
    for (int w = 0; w < 3; ++w) {
        const int item = t + w * 512;
        const int r = item >> 8;
        const int g = item & 255;
        const int e = offs[r * 260 + g + 1];
        int k = offs[r * 260 + g];
        const int* __restrict__ ip = idx + r * N_GENERA;
        float sa = 0.f, sb = 0.f;
        for (; k + 4 <= e; k += 4) {
            int i0 = ip[k], i1 = ip[k + 1], i2 = ip[k + 2], i3 = ip[k + 3];
            float2 v0 = Fl2[i0], v1 = Fl2[i1], v2 = Fl2[i2], v3 = Fl2[i3];
            sa += (v0.x + v1.x) + (v2.x + v3.x);
            sb += (v0.y + v1.y) + (v2.y + v3.y);
        }
        for (; k < e; ++k) {
            float2 v = Fl2[ip[k]];
            sa += v.x; sb += v.y;
        }
        float2 sp; sp.x = sa; sp.y = sb;
        ext2[item] = sp;
    }
    __syncthreads();

    f32x4* __restrict__ op0 = reinterpret_cast<f32x4*>(out) + (size_t)b0 * NF4;
    f32x4* __restrict__ op1 = op0 + NF4;
    #pragma unroll
    for (int kk = 0; kk < 14; ++kk) {
        const int q = kk * 512 + t;
        short4 s4 = *reinterpret_cast<const short4*>(sidx + q * 4);
        float2 p0 = ext2[s4.x];
        float2 p1 = ext2[s4.y];
        float2 p2 = ext2[s4.z];
        float2 p3 = ext2[s4.w];
        f32x4 va, vb;
        va[0] = p0.x; va[1] = p1.x; va[2] = p2.x; va[3] = p3.x;
        vb[0] = p0.y; vb[1] = p1.y; vb[2] = p2.y; vb[3] = p3.y;
        op0[q] = va;
        op1[q] = vb;
    }
}

extern "C" void kernel_launch(void* const* d_in, const int* in_sizes, int n_in,
                              void* d_out, int out_size, void* d_ws, size_t ws_size,
                              hipStream_t stream) {
    const float* F      = (const float*)d_in[0];
    const int*   labels = (const int*)d_in[1];
    float*       out    = (float*)d_out;

    const int B = in_sizes[0] / N_GENERA;  // 1024
    char* ws = (char*)d_ws;
    int*    idx  = (int*)(ws + WS_IDX_OFF);
    int*    offs = (int*)(ws + WS_OFFS_OFF);
    short*  sidx = (short*)(ws + WS_SIDX_OFF);
    float2* segW = (float2*)(ws + WS_SEG_OFF);

    const size_t ws_need = (size_t)WS_SEG_OFF + (size_t)(B / 2) * SEG_SZ * sizeof(float2);
    const int sidx_blocks = NF / 256;   // 112

    prep_kernel<<<dim3(N_RANKS + sidx_blocks), dim3(256), 0, stream>>>(labels, idx, offs, sidx);

    if (ws_size >= ws_need && (B % 2) == 0) {
        seg_kernel<<<dim3(B / 2), dim3(512), 0, stream>>>(F, idx, offs, segW);
        gather_kernel<<<dim3(B / 2), dim3(512), 0, stream>>>(F, segW, sidx, out);
    } else {
        fused_kernel<<<dim3(B / 2), dim3(512), 0, stream>>>(F, idx, offs, sidx, out);
    }
}

// Round 10
// 47.241 us; speedup vs baseline: 1.4983x; 1.0049x over previous
//
#include <hip/hip_runtime.h>

#define N_GENERA 4096
#define N_RANKS 6
#define N_GROUPS 256
#define NCH 7                         // 6 ranks + identity channel
#define SEG_SZ (N_RANKS * N_GROUPS)   // 1536
#define EXT_SZ (SEG_SZ + N_GENERA)    // 5632 pairs = 45 KB as float2
#define NF (N_GENERA * NCH)           // 28672 output floats per b
#define NF4 (NF / 4)                  // 7168 float4 per b

typedef float f32x4 __attribute__((ext_vector_type(4)));

// ws layout (identical to round-2 best):
//   idx  [6][4096] int   @ 0        (96 KB)
//   offs [6][260]  int   @ 98304    (6.1 KB)
//   sidx [NF]      short @ 104704   (56 KB)
#define WS_IDX_OFF  0
#define WS_OFFS_OFF 98304
#define WS_SIDX_OFF 104704

// ---------- Kernel 0: prep = per-rank CSR (blocks 0..5) + sidx map (blocks 6..117) ----------
__global__ __launch_bounds__(256) void prep_kernel(
    const int* __restrict__ labels,
    int* __restrict__ idx,      // [R][N_GENERA]
    int* __restrict__ offs,     // [R][260]
    short* __restrict__ sidx)   // [NF]
{
    const int t = threadIdx.x;

    if (blockIdx.x < N_RANKS) {
        const int r = blockIdx.x;
        const int* __restrict__ lab = labels + r * N_GENERA;

        __shared__ int cnt[N_GROUPS];
        __shared__ int scan[N_GROUPS];
        __shared__ int cur[N_GROUPS];

        cnt[t] = 0;
        __syncthreads();
        for (int i = t; i < N_GENERA; i += 256)
            atomicAdd(&cnt[lab[i]], 1);
        __syncthreads();

        int v = cnt[t];
        scan[t] = v;
        __syncthreads();
        #pragma unroll
        for (int s = 1; s < 256; s <<= 1) {
            int add = (t >= s) ? scan[t - s] : 0;
            __syncthreads();
            scan[t] += add;
            __syncthreads();
        }
        int start = scan[t] - v;          // exclusive prefix
        cur[t] = start;
        offs[r * 260 + t] = start;
        if (t == 0) offs[r * 260 + 256] = N_GENERA;
        __syncthreads();
        for (int i = t; i < N_GENERA; i += 256) {
            int p = atomicAdd(&cur[lab[i]], 1);
            idx[r * N_GENERA + p] = i;
        }
    } else {
        // sidx: output-float -> ext[]-index map (batch-independent)
        const int f = (blockIdx.x - N_RANKS) * 256 + t;   // < NF
        const int j = f / NCH;
        const int ch = f - j * NCH;
        int v;
        if (ch < N_RANKS)
            v = ch * N_GROUPS + labels[ch * N_GENERA + j];
        else
            v = SEG_SZ + j;               // identity channel -> F slot
        sidx[f] = (short)v;
    }
}

// ---------- shared device pieces (byte-identical inner loops to round 2) ----------
__device__ __forceinline__ void stage_write(float2* ext2, int t,
                                            f32x4 a0, f32x4 c0, f32x4 a1, f32x4 c1)
{
    f32x4* Flv = reinterpret_cast<f32x4*>(ext2 + SEG_SZ);
    f32x4 lo, hi;
    lo[0] = a0[0]; lo[1] = c0[0]; lo[2] = a0[1]; lo[3] = c0[1];
    hi[0] = a0[2]; hi[1] = c0[2]; hi[2] = a0[3]; hi[3] = c0[3];
    Flv[2 * t]     = lo;
    Flv[2 * t + 1] = hi;
    lo[0] = a1[0]; lo[1] = c1[0]; lo[2] = a1[1]; lo[3] = c1[1];
    hi[0] = a1[2]; hi[1] = c1[2]; hi[2] = a1[3]; hi[3] = c1[3];
    Flv[2 * (t + 512)]     = lo;
    Flv[2 * (t + 512) + 1] = hi;
}

__device__ __forceinline__ void phaseA(float2* ext2,
                                       const int* __restrict__ idx,
                                       const int* __restrict__ offs, int t)
{
    const float2* __restrict__ Fl2 = ext2 + SEG_SZ;
    #pragma unroll
    for (int w = 0; w < 3; ++w) {
        const int item = t + w * 512;
        const int r = item >> 8;
        const int g = item & 255;
        const int e = offs[r * 260 + g + 1];   // g==255 -> offs[r][256]==4096
        int k = offs[r * 260 + g];
        const int* __restrict__ ip = idx + r * N_GENERA;
        float sa = 0.f, sb = 0.f;
        for (; k + 4 <= e; k += 4) {
            int i0 = ip[k], i1 = ip[k + 1], i2 = ip[k + 2], i3 = ip[k + 3];
            float2 v0 = Fl2[i0], v1 = Fl2[i1], v2 = Fl2[i2], v3 = Fl2[i3];
            sa += (v0.x + v1.x) + (v2.x + v3.x);
            sb += (v0.y + v1.y) + (v2.y + v3.y);
        }
        for (; k < e; ++k) {
            float2 v = Fl2[ip[k]];
            sa += v.x; sb += v.y;
        }
        float2 sp; sp.x = sa; sp.y = sb;
        ext2[item] = sp;   // seg region; disjoint from F region being read
    }
}

__device__ __forceinline__ void phaseB(const float2* ext2,
                                       const short* __restrict__ sidx,
                                       float* __restrict__ out, int b0, int t)
{
    f32x4* __restrict__ op0 = reinterpret_cast<f32x4*>(out) + (size_t)b0 * NF4;
    f32x4* __restrict__ op1 = op0 + NF4;
    #pragma unroll
    for (int kk = 0; kk < 14; ++kk) {
        const int q = kk * 512 + t;
        short4 s4 = *reinterpret_cast<const short4*>(sidx + q * 4);
        float2 p0 = ext2[s4.x];
        float2 p1 = ext2[s4.y];
        float2 p2 = ext2[s4.z];
        float2 p3 = ext2[s4.w];
        f32x4 va, vb;
        va[0] = p0.x; va[1] = p1.x; va[2] = p2.x; va[3] = p3.x;
        vb[0] = p0.y; vb[1] = p1.y; vb[2] = p2.y; vb[3] = p3.y;
        op0[q] = va;
        op1[q] = vb;
    }
}

// ---------- Kernel 1: fused2 = TWO pairs per block, phase-overlapped ----------
// 256 blocks (1/CU), 512 threads, 45 KB LDS. Pair1's F loads are ISSUED into
// registers right after pair0's stage: their HBM latency hides under A0+B0,
// and pair0's 224 KB store burst drains under writeLDS1+A1 (stores are
// fire-and-forget; the e-reg waitcnt does not drain stores). This staggers
// load and store phases that were previously chip-wide synchronized.
__global__ __launch_bounds__(512) void fused2_kernel(
    const float* __restrict__ F,
    const int* __restrict__ idx,
    const int* __restrict__ offs,
    const short* __restrict__ sidx,
    float* __restrict__ out)
{
    __shared__ float2 ext2[EXT_SZ];
    const int t = threadIdx.x;
    const int b0 = blockIdx.x * 4;

    // stage pair0 (rows b0, b0+1)
    const f32x4* Fv0 = reinterpret_cast<const f32x4*>(F + (size_t)b0 * N_GENERA);
    const f32x4* Fv1 = reinterpret_cast<const f32x4*>(F + (size_t)(b0 + 1) * N_GENERA);
    {
        const f32x4 a0 = __builtin_nontemporal_load(Fv0 + t);
        const f32x4 c0 = __builtin_nontemporal_load(Fv1 + t);
        const f32x4 a1 = __builtin_nontemporal_load(Fv0 + t + 512);
        const f32x4 c1 = __builtin_nontemporal_load(Fv1 + t + 512);
        stage_write(ext2, t, a0, c0, a1, c1);
    }

    // issue pair1 loads EARLY (held in 16 VGPR across A0+B0; 1 block/CU so
    // VGPR pressure cannot cost occupancy — r8's failure mode excluded)
    const f32x4* Fv2 = reinterpret_cast<const f32x4*>(F + (size_t)(b0 + 2) * N_GENERA);
    const f32x4* Fv3 = reinterpret_cast<const f32x4*>(F + (size_t)(b0 + 3) * N_GENERA);
    const f32x4 e0 = __builtin_nontemporal_load(Fv2 + t);
    const f32x4 g0 = __builtin_nontemporal_load(Fv3 + t);
    const f32x4 e1 = __builtin_nontemporal_load(Fv2 + t + 512);
    const f32x4 g1 = __builtin_nontemporal_load(Fv3 + t + 512);

    __syncthreads();
    phaseA(ext2, idx, offs, t);
    __syncthreads();
    phaseB(ext2, sidx, out, b0, t);
    __syncthreads();                     // all waves done reading pair0 F region

    stage_write(ext2, t, e0, g0, e1, g1);
    __syncthreads();
    phaseA(ext2, idx, offs, t);
    __syncthreads();
    phaseB(ext2, sidx, out, b0 + 2, t);
}

// ---------- Fallback: round-2 fused kernel (B not divisible by 4) ----------
__global__ __launch_bounds__(512) void fused_kernel(
    const float* __restrict__ F,
    const int* __restrict__ idx,
    const int* __restrict__ offs,
    const short* __restrict__ sidx,
    float* __restrict__ out)
{
    __shared__ float2 ext2[EXT_SZ];
    const int b0 = blockIdx.x * 2;
    const int t = threadIdx.x;

    const f32x4* Fv0 = reinterpret_cast<const f32x4*>(F + (size_t)b0 * N_GENERA);
    const f32x4* Fv1 = reinterpret_cast<const f32x4*>(F + (size_t)(b0 + 1) * N_GENERA);
    {
        const f32x4 a0 = __builtin_nontemporal_load(Fv0 + t);
        const f32x4 c0 = __builtin_nontemporal_load(Fv1 + t);
        const f32x4 a1 = __builtin_nontemporal_load(Fv0 + t + 512);
        const f32x4 c1 = __builtin_nontemporal_load(Fv1 + t + 512);
        stage_write(ext2, t, a0, c0, a1, c1);
    }
    __syncthreads();
    phaseA(ext2, idx, offs, t);
    __syncthreads();
    phaseB(ext2, sidx, out, b0, t);
}

extern "C" void kernel_launch(void* const* d_in, const int* in_sizes, int n_in,
                              void* d_out, int out_size, void* d_ws, size_t ws_size,
                              hipStream_t stream) {
    const float* F      = (const float*)d_in[0];
    const int*   labels = (const int*)d_in[1];
    float*       out    = (float*)d_out;

    const int B = in_sizes[0] / N_GENERA;  // 1024
    char* ws = (char*)d_ws;
    int*   idx  = (int*)(ws + WS_IDX_OFF);
    int*   offs = (int*)(ws + WS_OFFS_OFF);
    short* sidx = (short*)(ws + WS_SIDX_OFF);

    const int sidx_blocks = NF / 256;   // 112
    prep_kernel<<<dim3(N_RANKS + sidx_blocks), dim3(256), 0, stream>>>(labels, idx, offs, sidx);

    if ((B % 4) == 0)
        fused2_kernel<<<dim3(B / 4), dim3(512), 0, stream>>>(F, idx, offs, sidx, out);
    else
        fused_kernel<<<dim3(B / 2), dim3(512), 0, stream>>>(F, idx, offs, sidx, out);
}